// Round 2
// baseline (838.519 us; speedup 1.0000x reference)
//
#include <hip/hip_runtime.h>
#include <stdint.h>

#define B_    64
#define H_    16384
#define NB_   512
#define NNZ_  26214
#define N_IN_ 1024
#define N_OUT_ 1024

#define PADW 36   // s_w row stride (floats): keeps float4 reads 16B-aligned
#define PADX 68   // s_x row stride

// ---------------- index build (tiny, graph-safe, redone every call) ---------

__global__ void zero_cnt(int* __restrict__ cnt) {
    cnt[threadIdx.x] = 0;
}

__global__ void hist(const int* __restrict__ rows, int* __restrict__ cnt) {
    int n = blockIdx.x * 256 + threadIdx.x;
    if (n < NNZ_) atomicAdd(&cnt[rows[n]], 1);
}

// single block, 512 threads: exclusive scan of cnt -> ptr; re-zero cnt
__global__ void scan_k(int* __restrict__ cnt, int* __restrict__ ptr) {
    __shared__ int tmp[NB_];
    int t = threadIdx.x;
    tmp[t] = cnt[t];
    __syncthreads();
    for (int off = 1; off < NB_; off <<= 1) {
        int v = (t >= off) ? tmp[t - off] : 0;
        __syncthreads();
        tmp[t] += v;
        __syncthreads();
    }
    if (t == 0) ptr[0] = 0;
    ptr[t + 1] = tmp[t];
    cnt[t] = 0;
}

__global__ void scatter(const int* __restrict__ rows, const int* __restrict__ ptr,
                        int* __restrict__ cnt, int* __restrict__ perm) {
    int n = blockIdx.x * 256 + threadIdx.x;
    if (n < NNZ_) {
        int r = rows[n];
        int pos = ptr[r] + atomicAdd(&cnt[r], 1);
        perm[pos] = n;
    }
}

// ---------------- state init ------------------------------------------------

// hs[b][h] = (h < N_IN) ? inp[b][h] : 0   (all f32)
__global__ void init_hs(const float* __restrict__ inp, float* __restrict__ hs) {
    int idx = blockIdx.x * 256 + threadIdx.x;   // 0 .. B*H-1
    int b = idx >> 14;
    int h = idx & (H_ - 1);
    hs[idx] = (h < N_IN_) ? inp[b * N_IN_ + h] : 0.0f;
}

// ---------------- step kernel ----------------------------------------------
// One WG (256 thr, 4 waves) per row-block r.
//   y[b][r*32+i] = act( sum_{n in row r} W_n @ x[:, col(n)*32..+32] + bias )
// Thread tiling: jh = K-half (j in [16*jh,16*jh+16)), within half:
//   4 batches x 4 rows register tile. Halves reduced via LDS at the end.
template <bool SIG, bool LAST>
__global__ void step_k(const float* __restrict__ x, float* __restrict__ y,
                       float* __restrict__ out,
                       const float* __restrict__ blocks,
                       const float* __restrict__ bias,
                       const int* __restrict__ cols,
                       const int* __restrict__ perm,
                       const int* __restrict__ ptr,
                       int row_base, int col_limit) {
    __shared__ float s_w[32][PADW];   // s_w[j][i] = W[i][j]   (transposed)
    __shared__ float s_x[32][PADX];   // s_x[j][b] = x[b][c*32+j] (transposed)

    const int r   = blockIdx.x + row_base;
    const int tid = threadIdx.x;
    const int jh  = tid >> 7;            // 0/1
    const int t   = tid & 127;
    const int b0  = (t >> 3) << 2;       // 0,4,...,60
    const int ig  = (t & 7) << 2;        // 0,4,...,28

    float acc[4][4] = {{0.f,0.f,0.f,0.f},{0.f,0.f,0.f,0.f},
                       {0.f,0.f,0.f,0.f},{0.f,0.f,0.f,0.f}};

    const int beg = ptr[r], end = ptr[r + 1];
    for (int k = beg; k < end; ++k) {
        const int n = perm[k];
        const int c = cols[n];            // workgroup-uniform
        if (c >= col_limit) continue;     // uniform branch: barrier-safe

        // stage W transposed: each thread loads W row i, cols j0..j0+3
        {
            const float4 w4 = ((const float4*)(blocks + (size_t)n * 1024))[tid];
            const int i  = tid >> 3;          // 0..31
            const int j0 = (tid & 7) << 2;    // 0,4,..,28
            s_w[j0 + 0][i] = w4.x;
            s_w[j0 + 1][i] = w4.y;
            s_w[j0 + 2][i] = w4.z;
            s_w[j0 + 3][i] = w4.w;
        }
        // stage x slab transposed: 64 batches x 32 cols, 512 float4 loads
        {
            const float* xb = x + (size_t)c * 32;
            #pragma unroll
            for (int q = 0; q < 2; ++q) {
                const int idx = tid + q * 256;   // 0..511
                const int b   = idx >> 3;        // 0..63
                const int j0  = (idx & 7) << 2;  // 0,4,..,28
                float4 v = *(const float4*)(xb + (size_t)b * H_ + j0);
                s_x[j0 + 0][b] = v.x;
                s_x[j0 + 1][b] = v.y;
                s_x[j0 + 2][b] = v.z;
                s_x[j0 + 3][b] = v.w;
            }
        }
        __syncthreads();

        #pragma unroll
        for (int jj = 0; jj < 16; ++jj) {
            const int j = (jh << 4) + jj;
            const float4 wv = *(const float4*)&s_w[j][ig];
            const float4 xv = *(const float4*)&s_x[j][b0];
            acc[0][0] += wv.x * xv.x; acc[0][1] += wv.y * xv.x;
            acc[0][2] += wv.z * xv.x; acc[0][3] += wv.w * xv.x;
            acc[1][0] += wv.x * xv.y; acc[1][1] += wv.y * xv.y;
            acc[1][2] += wv.z * xv.y; acc[1][3] += wv.w * xv.y;
            acc[2][0] += wv.x * xv.z; acc[2][1] += wv.y * xv.z;
            acc[2][2] += wv.z * xv.z; acc[2][3] += wv.w * xv.z;
            acc[3][0] += wv.x * xv.w; acc[3][1] += wv.y * xv.w;
            acc[3][2] += wv.z * xv.w; acc[3][3] += wv.w * xv.w;
        }
        __syncthreads();
    }

    // reduce the two j-halves through LDS (reuse s_x: 2176 >= 2048 floats)
    float* red = &s_x[0][0];
    if (jh == 1) {
        #pragma unroll
        for (int bi = 0; bi < 4; ++bi)
            #pragma unroll
            for (int ii = 0; ii < 4; ++ii)
                red[(t << 4) + (bi << 2) + ii] = acc[bi][ii];
    }
    __syncthreads();
    if (jh == 0) {
        #pragma unroll
        for (int bi = 0; bi < 4; ++bi) {
            #pragma unroll
            for (int ii = 0; ii < 4; ++ii) {
                float v = acc[bi][ii] + red[(t << 4) + (bi << 2) + ii]
                        + bias[r * 32 + ig + ii];
                if (SIG) v = 1.0f / (1.0f + __expf(-v));
                if (LAST) {
                    float s = 1.0f / (1.0f + __expf(-v));
                    int kk = (r - (NB_ - N_OUT_ / 32)) * 32 + ig + ii;
                    out[(size_t)(b0 + bi) * N_OUT_ + kk] = s;
                } else {
                    y[(size_t)(b0 + bi) * H_ + r * 32 + ig + ii] = v;
                }
            }
        }
    }
}

// ---------------- launcher --------------------------------------------------

extern "C" void kernel_launch(void* const* d_in, const int* in_sizes, int n_in,
                              void* d_out, int out_size, void* d_ws, size_t ws_size,
                              hipStream_t stream) {
    const float* inp    = (const float*)d_in[0];
    const float* blocks = (const float*)d_in[1];
    const float* bias   = (const float*)d_in[2];
    const int*   rows   = (const int*)d_in[3];
    const int*   cols   = (const int*)d_in[4];
    float*       out    = (float*)d_out;

    char* ws = (char*)d_ws;
    float* hs0    = (float*)ws;                              // 4 MB
    float* hs1    = (float*)(ws + 4u * 1024 * 1024);         // 4 MB
    int*   rowptr = (int*)(ws + 8u * 1024 * 1024);           // 513 ints
    int*   rowcnt = (int*)(ws + 8u * 1024 * 1024 + 4096);    // 512 ints
    int*   perm   = (int*)(ws + 8u * 1024 * 1024 + 8192);    // NNZ ints

    zero_cnt<<<1, NB_, 0, stream>>>(rowcnt);
    hist<<<(NNZ_ + 255) / 256, 256, 0, stream>>>(rows, rowcnt);
    scan_k<<<1, NB_, 0, stream>>>(rowcnt, rowptr);
    scatter<<<(NNZ_ + 255) / 256, 256, 0, stream>>>(rows, rowptr, rowcnt, perm);

    init_hs<<<(B_ * H_) / 256, 256, 0, stream>>>(inp, hs0);

    // step 0: input nonzero only in first 32 col-blocks
    step_k<true, false><<<NB_, 256, 0, stream>>>(hs0, hs1, nullptr, blocks, bias,
                                                 cols, perm, rowptr, 0, 32);
    // steps 1..6
    float* cur = hs1; float* nxt = hs0;
    for (int s = 1; s < 7; ++s) {
        step_k<true, false><<<NB_, 256, 0, stream>>>(cur, nxt, nullptr, blocks, bias,
                                                     cols, perm, rowptr, 0, NB_);
        float* tptr = cur; cur = nxt; nxt = tptr;
    }
    // step 7: only rows 480..511 feed the output; fused final sigmoid
    step_k<false, true><<<N_OUT_ / 32, 256, 0, stream>>>(cur, nxt, out, blocks, bias,
                                                         cols, perm, rowptr,
                                                         NB_ - N_OUT_ / 32, NB_);
}